// Round 10
// baseline (1022.948 us; speedup 1.0000x reference)
//
#include <hip/hip_runtime.h>

#define N_ 32
#define C_ 64
#define T_ 64
#define V_ 204
#define H_ 3
#define TV_ (T_ * V_)          // 13056
#define CTV_ (C_ * TV_)        // 835584
#define NH_ (N_ * H_)          // 96
#define EPS_ 1e-5f
#define ATT_SC_ (1.0f / 3264.0f)
#define STV_ (H_ * TV_)        // 39168
#define KP_ 224                // padded K (v) for MFMA
#define UP_ 208                // padded u rows of A

typedef __bf16 bf16x8 __attribute__((ext_vector_type(8)));
typedef __bf16 bf16x4 __attribute__((ext_vector_type(4)));
typedef float  f32x4  __attribute__((ext_vector_type(4)));

// ---------------------------------------------------------------------------
// K0_all: fused conversions (286 blocks x 256 = 73216 threads)
//   i < 46592:  Apad = bf16(A) zero-padded (208x224)
//   next 6144:  Wbf = bf16(qkv_w)                          (96x64)
//   next 12288: onw_bf[(s*64+o)][c] = bf16(on_w[o][s*64+c]) (192x64)
//   next 4096:  Wg  = bf16(gcn_w)                          (64x64)
//   next 4096:  Wf  = bf16(ff_w)                           (64x64)
// ---------------------------------------------------------------------------
__global__ __launch_bounds__(256) void k0_all(
    const float* __restrict__ A, const float* __restrict__ qw,
    const float* __restrict__ onw, const float* __restrict__ gw,
    const float* __restrict__ fw,
    __bf16* __restrict__ Apad, __bf16* __restrict__ Wbf,
    __bf16* __restrict__ onw_bf, __bf16* __restrict__ Wg,
    __bf16* __restrict__ Wf)
{
    const int i = blockIdx.x * 256 + threadIdx.x;   // 0..73215
    if (i < UP_ * KP_) {
        const int u = i / KP_, v = i % KP_;
        const float val = (u < V_ && v < V_) ? A[u * V_ + v] : 0.f;
        Apad[i] = (__bf16)val;
    } else {
        const int j = i - UP_ * KP_;                // 0..26623
        if (j < 96 * C_) {
            Wbf[j] = (__bf16)qw[j];
        } else if (j < 96 * C_ + 192 * C_) {
            const int k = j - 96 * C_;              // 0..12287
            const int c = k & 63, r = k >> 6, o = r & 63, s = r >> 6;
            onw_bf[k] = (__bf16)onw[o * 192 + s * 64 + c];
        } else if (j < 96 * C_ + 192 * C_ + 64 * C_) {
            const int k = j - (96 * C_ + 192 * C_); // 0..4095
            Wg[k] = (__bf16)gw[k];
        } else {
            const int k = j - (96 * C_ + 192 * C_ + 64 * C_); // 0..4095
            Wf[k] = (__bf16)fw[k];
        }
    }
}

// ---------------------------------------------------------------------------
// K1 (fused, double MFMA): per (n,t) block
//   MFMA1: h[v][c] = sum_a x[n,a,t,v] * Wg[c,a] -> +bias -> bf16 hs[c][v] LDS
//   MFMA2: G[c][u] = sum_v Apad[u,v] * hs[c,v]
//   epilogue: val = relu(G*s1+sh+x); staged via LDS (2 halves, reusing hs
//   region as f32) so global stores are contiguous full-line writes.
// ---------------------------------------------------------------------------
__global__ __launch_bounds__(256) void k1_fused(
    const float* __restrict__ x, const __bf16* __restrict__ Wg,
    const float* __restrict__ gb, const __bf16* __restrict__ Apad,
    const float* __restrict__ bng, const float* __restrict__ bnb,
    const float* __restrict__ bnm, const float* __restrict__ bnv,
    float* __restrict__ g_out)
{
    __shared__ __bf16 hs[C_][232];                 // 29,696 B; reused as f32 below
    float* lds_f = (float*)&hs[0][0];
    const int t = blockIdx.x, n = blockIdx.y;
    const int tid = threadIdx.x;
    const int wave = tid >> 6, lane = tid & 63;
    const int l16 = lane & 15, quad = lane >> 4;

    // zero hs cols 208..223 (read by MFMA2 kc=6; x Apad zeros, must be finite)
    if (tid < 128) {
        const int c = tid >> 1, half = tid & 1;
        int* zp = (int*)&hs[c][208 + half * 8];
        zp[0] = 0; zp[1] = 0; zp[2] = 0; zp[3] = 0;
    }

    const int cB = wave * 16 + l16;          // this lane's c row (B-side)

    // ---- MFMA1 ----
    bf16x8 wfrag[2];
#pragma unroll
    for (int kc = 0; kc < 2; ++kc)
        wfrag[kc] = *(const bf16x8*)(Wg + (size_t)cB * C_ + kc * 32 + quad * 8);

    const float* xrow = x + (size_t)n * CTV_ + (size_t)t * V_;
    f32x4 acc[13];
#pragma unroll
    for (int i = 0; i < 13; ++i) acc[i] = (f32x4){0.f, 0.f, 0.f, 0.f};

#pragma unroll 1
    for (int vt = 0; vt < 13; ++vt) {
        const int v = vt * 16 + l16;
#pragma unroll
        for (int kc = 0; kc < 2; ++kc) {
            bf16x8 af;
#pragma unroll
            for (int e = 0; e < 8; ++e) af[e] = (__bf16)0.f;
            if (v < V_) {
                const float* xp = xrow + v + (size_t)(kc * 32 + quad * 8) * TV_;
#pragma unroll
                for (int e = 0; e < 8; ++e) af[e] = (__bf16)xp[(size_t)e * TV_];
            }
            acc[vt] = __builtin_amdgcn_mfma_f32_16x16x32_bf16(af, wfrag[kc], acc[vt], 0, 0, 0);
        }
    }

    // bias + pack to hs[c][v]
    const float biasc = gb[cB];
#pragma unroll
    for (int vt = 0; vt < 13; ++vt) {
        const int v0 = vt * 16 + quad * 4;
        bf16x4 hv;
#pragma unroll
        for (int i = 0; i < 4; ++i) hv[i] = (__bf16)(acc[vt][i] + biasc);
        *(bf16x4*)&hs[cB][v0] = hv;
    }
    __syncthreads();

    // ---- MFMA2 ----
#pragma unroll
    for (int i = 0; i < 13; ++i) acc[i] = (f32x4){0.f, 0.f, 0.f, 0.f};

    const __bf16* hrow = &hs[cB][0];
#pragma unroll 1
    for (int kc = 0; kc < 7; ++kc) {
        const bf16x8 bh = *(const bf16x8*)(hrow + kc * 32 + quad * 8);
#pragma unroll
        for (int ut = 0; ut < 13; ++ut) {
            const bf16x8 aA = *(const bf16x8*)(Apad + (size_t)(ut * 16 + l16) * KP_ + kc * 32 + quad * 8);
            acc[ut] = __builtin_amdgcn_mfma_f32_16x16x32_bf16(aA, bh, acc[ut], 0, 0, 0);
        }
    }

    // epilogue compute: val[ut] = relu(G*s1 + sh + x) in regs (overwrite acc)
    const float s1 = bng[cB] * rsqrtf(bnv[cB] + EPS_);
    const float sh = bnb[cB] - bnm[cB] * s1;
    const float* xres = x + (size_t)n * CTV_ + (size_t)cB * TV_ + (size_t)t * V_;
#pragma unroll
    for (int ut = 0; ut < 13; ++ut) {
        const int u0 = ut * 16 + quad * 4;
        if (u0 < V_) {
            const float4 x4 = *(const float4*)(xres + u0);
            acc[ut][0] = fmaxf(acc[ut][0] * s1 + sh + x4.x, 0.f);
            acc[ut][1] = fmaxf(acc[ut][1] * s1 + sh + x4.y, 0.f);
            acc[ut][2] = fmaxf(acc[ut][2] * s1 + sh + x4.z, 0.f);
            acc[ut][3] = fmaxf(acc[ut][3] * s1 + sh + x4.w, 0.f);
        }
    }

    // staged stores: 2 halves of 32 c-rows; LDS f32 half-tile = 26,112 B
#pragma unroll 1
    for (int half = 0; half < 2; ++half) {
        __syncthreads();
        if ((wave >> 1) == half) {
            const int row = cB - half * 32;      // 0..31
#pragma unroll
            for (int ut = 0; ut < 13; ++ut) {
                const int u0 = ut * 16 + quad * 4;
                if (u0 < V_)
                    *(f32x4*)&lds_f[row * 204 + u0] = acc[ut];
            }
        }
        __syncthreads();
        // cooperative contiguous store: 32 rows x 51 float4
        float* gbase = g_out + (size_t)n * CTV_ + (size_t)(half * 32) * TV_ + (size_t)t * V_;
#pragma unroll 1
        for (int i = tid; i < 1632; i += 256) {
            const int row = i / 51, col = i - row * 51;
            *(float4*)(gbase + (size_t)row * TV_ + col * 4) = ((float4*)lds_f)[i];
        }
    }
}

// ---------------------------------------------------------------------------
// K2 (MFMA): qk[(n,tv), j] = sum_c bf16(g+pe)[tv,c] * Wbf[j,c] + qb[j]
// ---------------------------------------------------------------------------
__global__ __launch_bounds__(256) void k2_mfma(
    const float* __restrict__ g_ws, const float* __restrict__ pe,
    const __bf16* __restrict__ Wbf, const float* __restrict__ qb,
    float* __restrict__ qk_ws)
{
    const int bx  = blockIdx.x;            // 0..6527
    const int n   = bx / 204;
    const int tvb = (bx % 204) * 64;
    const int wave = threadIdx.x >> 6;
    const int lane = threadIdx.x & 63;
    const int l16  = lane & 15;
    const int quad = lane >> 4;

    const int tv = tvb + wave * 16 + l16;
    const float* gp = g_ws + (size_t)n * CTV_ + tv;
    const float* pp = pe + tv;
    bf16x8 a[2];
#pragma unroll
    for (int kc = 0; kc < 2; ++kc) {
#pragma unroll
        for (int e = 0; e < 8; ++e) {
            const int c = kc * 32 + quad * 8 + e;
            a[kc][e] = (__bf16)(gp[(size_t)c * TV_] + pp[(size_t)c * TV_]);
        }
    }

    f32x4 acc[6];
#pragma unroll
    for (int jt = 0; jt < 6; ++jt) acc[jt] = (f32x4){0.f, 0.f, 0.f, 0.f};

#pragma unroll
    for (int kc = 0; kc < 2; ++kc) {
#pragma unroll
        for (int jt = 0; jt < 6; ++jt) {
            const bf16x8 b = *(const bf16x8*)(Wbf + (size_t)(jt * 16 + l16) * C_ + kc * 32 + quad * 8);
            acc[jt] = __builtin_amdgcn_mfma_f32_16x16x32_bf16(a[kc], b, acc[jt], 0, 0, 0);
        }
    }

    const int rrow = tvb + wave * 16 + quad * 4;
#pragma unroll
    for (int jt = 0; jt < 6; ++jt) {
        const int j = jt * 16 + l16;
        const float bias = qb[j];
        float* op = qk_ws + (size_t)(n * 96 + j) * TV_ + rrow;
        float4 o;
        o.x = acc[jt][0] + bias;
        o.y = acc[jt][1] + bias;
        o.z = acc[jt][2] + bias;
        o.w = acc[jt][3] + bias;
        *(float4*)op = o;
    }
}

// ---------------------------------------------------------------------------
// K3a: att partials; K3b: finalize + transpose to bf16 [n][q][s*64+t]
// ---------------------------------------------------------------------------
__global__ __launch_bounds__(64) void k3_att_part(
    const float* __restrict__ qk_ws, float* __restrict__ part)
{
    const int qcg = blockIdx.x;
    const int n = blockIdx.y;
    const int h  = blockIdx.z >> 2;
    const int wv = blockIdx.z & 3;
    const int q = threadIdx.x;
    float acc[16];
#pragma unroll
    for (int i = 0; i < 16; ++i) acc[i] = 0.f;

#pragma unroll 1
    for (int qc2 = 0; qc2 < 2; ++qc2) {
        const int qc = qcg * 2 + qc2;
        const float* Qp = qk_ws + (size_t)(n * 96 + h * 16 + qc) * TV_;
        const float* Kp = qk_ws + (size_t)(n * 96 + 48 + h * 16 + qc) * TV_;
#pragma unroll 1
        for (int vc = 0; vc < 3; ++vc) {
            const int v0 = vc * 68;
            float kr[68];
            const float* kp = Kp + (size_t)q * V_ + v0;
#pragma unroll
            for (int m = 0; m < 17; ++m) {
                float4 f = *(const float4*)(kp + m * 4);
                kr[m * 4 + 0] = f.x; kr[m * 4 + 1] = f.y;
                kr[m * 4 + 2] = f.z; kr[m * 4 + 3] = f.w;
            }
#pragma unroll 1
            for (int ti = 0; ti < 16; ++ti) {
                const int tt = wv * 16 + ti;
                const float* qp = Qp + (size_t)tt * V_ + v0;
                float a = acc[ti];
#pragma unroll
                for (int vv = 0; vv < 68; ++vv) a = fmaf(qp[vv], kr[vv], a);
                acc[ti] = a;
            }
        }
    }
    float* pp = part + ((size_t)qcg * NH_ + (size_t)(n * H_ + h)) * 4096;
#pragma unroll
    for (int ti = 0; ti < 16; ++ti) pp[(wv * 16 + ti) * 64 + q] = acc[ti];
}

__global__ __launch_bounds__(256) void k3_att_fin(
    const float* __restrict__ part, const float* __restrict__ alphas,
    const float* __restrict__ att1s, __bf16* __restrict__ att_bt)
{
    const int i = blockIdx.x * 256 + threadIdx.x;
    float s = 0.f;
#pragma unroll
    for (int p = 0; p < 8; ++p) s += part[(size_t)p * NH_ * 4096 + i];
    const int nh = i >> 12;
    const int h  = nh % H_;
    const int n  = nh / H_;
    const int tq = i & 4095;
    const int t  = tq >> 6;
    const int q  = tq & 63;
    const float val = tanhf(s * ATT_SC_) * alphas[h] + att1s[h * 4096 + tq];
    att_bt[((size_t)n * 64 + q) * 192 + h * 64 + t] = (__bf16)val;
}

// ---------------------------------------------------------------------------
// K4a (MFMA): P[np][(s*64+o)][tv] bf16 = sum_c onw_bf[(s,o)][c] * g[np][c][tv]
// ---------------------------------------------------------------------------
__global__ __launch_bounds__(256) void k4a_mfma(
    const float* __restrict__ g_chunk, const __bf16* __restrict__ onw_bf,
    __bf16* __restrict__ P)
{
    const int tvt = blockIdx.x;        // 0..203
    const int np  = blockIdx.y;        // 0..15
    const int wave = threadIdx.x >> 6;
    const int lane = threadIdx.x & 63;
    const int l16  = lane & 15;
    const int quad = lane >> 4;
    const int tv = tvt * 64 + wave * 16 + l16;

    const float* gp = g_chunk + (size_t)np * CTV_ + tv;
    bf16x8 b[2];
#pragma unroll
    for (int kc = 0; kc < 2; ++kc) {
#pragma unroll
        for (int e = 0; e < 8; ++e)
            b[kc][e] = (__bf16)gp[(size_t)(kc * 32 + quad * 8 + e) * TV_];
    }

    __bf16* Pp = P + (size_t)np * 192 * TV_ + tv;
#pragma unroll
    for (int mt = 0; mt < 12; ++mt) {
        f32x4 acc = (f32x4){0.f, 0.f, 0.f, 0.f};
#pragma unroll
        for (int kc = 0; kc < 2; ++kc) {
            const bf16x8 a = *(const bf16x8*)(onw_bf + (mt * 16 + l16) * C_ + kc * 32 + quad * 8);
            acc = __builtin_amdgcn_mfma_f32_16x16x32_bf16(a, b[kc], acc, 0, 0, 0);
        }
#pragma unroll
        for (int i = 0; i < 4; ++i)
            Pp[(size_t)(mt * 16 + quad * 4 + i) * TV_] = (__bf16)acc[i];
    }
}

// ---------------------------------------------------------------------------
// K4b (MFMA): y[q,v] per (np,o) = sum_{k=0..191} att_bt[q][k] * P[(s,o)][t,v]
// ---------------------------------------------------------------------------
__global__ __launch_bounds__(256) void k4b_mfma(
    const __bf16* __restrict__ P,
    const __bf16* __restrict__ att_bt_chunk,   // [np][q][192]
    const float* __restrict__ g_chunk,
    const float* __restrict__ onb,
    const float* __restrict__ bng, const float* __restrict__ bnb,
    const float* __restrict__ bnm, const float* __restrict__ bnv,
    float* __restrict__ out_chunk)
{
    const int o  = blockIdx.x;   // 0..63
    const int np = blockIdx.y;   // 0..15
    const int wave = threadIdx.x >> 6;
    const int lane = threadIdx.x & 63;
    const int l16  = lane & 15;
    const int quad = lane >> 4;
    const int q0 = wave * 16;

    const __bf16* ap = att_bt_chunk + ((size_t)np * 64 + q0 + l16) * 192 + quad * 8;
    bf16x8 a[6];
#pragma unroll
    for (int kk = 0; kk < 6; ++kk) a[kk] = *(const bf16x8*)(ap + kk * 32);

    const __bf16* bp[6];
#pragma unroll
    for (int kk = 0; kk < 6; ++kk)
        bp[kk] = P + ((size_t)np * 192 + (kk >> 1) * 64 + o) * TV_
                   + (size_t)((kk & 1) * 32 + quad * 8) * V_ + l16;

    f32x4 acc[13];
#pragma unroll
    for (int vt = 0; vt < 13; ++vt) acc[vt] = (f32x4){0.f, 0.f, 0.f, 0.f};

#pragma unroll
    for (int vt = 0; vt < 13; ++vt) {
#pragma unroll
        for (int kk = 0; kk < 6; ++kk) {
            bf16x8 b;
#pragma unroll
            for (int e = 0; e < 8; ++e) b[e] = bp[kk][e * V_ + vt * 16];
            acc[vt] = __builtin_amdgcn_mfma_f32_16x16x32_bf16(a[kk], b, acc[vt], 0, 0, 0);
        }
    }

    const float s1 = bng[o] * rsqrtf(bnv[o] + EPS_);
    const float sh = onb[o] * s1 + bnb[o] - bnm[o] * s1;
    const float* gp = g_chunk + (size_t)np * CTV_ + (size_t)o * TV_;
    float* zp = out_chunk + (size_t)np * CTV_ + (size_t)o * TV_;
    const int q = q0 + quad * 4;
#pragma unroll
    for (int vt = 0; vt < 13; ++vt) {
        const int v = vt * 16 + l16;
        if (v < V_) {
#pragma unroll
            for (int i = 0; i < 4; ++i) {
                float val = acc[vt][i] * s1 + sh + gp[(size_t)(q + i) * V_ + v];
                zp[(size_t)(q + i) * V_ + v] = (val > 0.f) ? val : 0.1f * val;
            }
        }
    }
}

// ---------------------------------------------------------------------------
// K5 (MFMA): out[(n,tv), o] = leaky(bn(sum_c y3[tv,c]*Wf[o,c] + fb) + g),
//   in-place on out; same structure as k2_mfma (N=64).
//   In-place safe: each wave gathers only its own 16 tv columns (loads
//   complete before MFMAs/stores), blocks/waves touch disjoint tv.
// ---------------------------------------------------------------------------
__global__ __launch_bounds__(256) void k5_mfma(
    const float* __restrict__ g_ws, const __bf16* __restrict__ Wf,
    const float* __restrict__ fb,
    const float* __restrict__ bng, const float* __restrict__ bnb,
    const float* __restrict__ bnm, const float* __restrict__ bnv,
    float* __restrict__ io)
{
    const int bx  = blockIdx.x;            // 0..6527
    const int n   = bx / 204;
    const int tvb = (bx % 204) * 64;
    const int wave = threadIdx.x >> 6;
    const int lane = threadIdx.x & 63;
    const int l16  = lane & 15;
    const int quad = lane >> 4;

    const int tv = tvb + wave * 16 + l16;
    const float* yp = io + (size_t)n * CTV_ + tv;
    bf16x8 a[2];
#pragma unroll
    for (int kc = 0; kc < 2; ++kc) {
#pragma unroll
        for (int e = 0; e < 8; ++e)
            a[kc][e] = (__bf16)yp[(size_t)(kc * 32 + quad * 8 + e) * TV_];
    }

    f32x4 acc[4];
#pragma unroll
    for (int jt = 0; jt < 4; ++jt) acc[jt] = (f32x4){0.f, 0.f, 0.f, 0.f};

#pragma unroll
    for (int kc = 0; kc < 2; ++kc) {
#pragma unroll
        for (int jt = 0; jt < 4; ++jt) {
            const bf16x8 b = *(const bf16x8*)(Wf + (size_t)(jt * 16 + l16) * C_ + kc * 32 + quad * 8);
            acc[jt] = __builtin_amdgcn_mfma_f32_16x16x32_bf16(a[kc], b, acc[jt], 0, 0, 0);
        }
    }

    const int rrow = tvb + wave * 16 + quad * 4;
#pragma unroll
    for (int jt = 0; jt < 4; ++jt) {
        const int o = jt * 16 + l16;
        const float s1 = bng[o] * rsqrtf(bnv[o] + EPS_);
        const float sh = fb[o] * s1 + bnb[o] - bnm[o] * s1;
        const float4 g4 = *(const float4*)(g_ws + (size_t)n * CTV_ + (size_t)o * TV_ + rrow);
        float* op = io + (size_t)n * CTV_ + (size_t)o * TV_ + rrow;
        float4 v;
        v.x = acc[jt][0] * s1 + sh + g4.x;
        v.y = acc[jt][1] * s1 + sh + g4.y;
        v.z = acc[jt][2] * s1 + sh + g4.z;
        v.w = acc[jt][3] * s1 + sh + g4.w;
        v.x = (v.x > 0.f) ? v.x : 0.1f * v.x;
        v.y = (v.y > 0.f) ? v.y : 0.1f * v.y;
        v.z = (v.z > 0.f) ? v.z : 0.1f * v.z;
        v.w = (v.w > 0.f) ? v.w : 0.1f * v.w;
        *(float4*)op = v;
    }
}

// ---------------------------------------------------------------------------
extern "C" void kernel_launch(void* const* d_in, const int* in_sizes, int n_in,
                              void* d_out, int out_size, void* d_ws, size_t ws_size,
                              hipStream_t stream)
{
    (void)in_sizes; (void)n_in; (void)out_size; (void)ws_size;
    const float* x      = (const float*)d_in[0];
    const float* A      = (const float*)d_in[1];
    const float* gcn_w  = (const float*)d_in[2];
    const float* gcn_b  = (const float*)d_in[3];
    const float* gcn_g  = (const float*)d_in[4];
    const float* gcn_bb = (const float*)d_in[5];
    const float* gcn_m  = (const float*)d_in[6];
    const float* gcn_v  = (const float*)d_in[7];
    const float* pe     = (const float*)d_in[8];
    const float* qkv_w  = (const float*)d_in[9];
    const float* qkv_b  = (const float*)d_in[10];
    const float* alphas = (const float*)d_in[11];
    const float* att1s  = (const float*)d_in[12];
    const float* on_w   = (const float*)d_in[13];
    const float* on_b   = (const float*)d_in[14];
    const float* on_g   = (const float*)d_in[15];
    const float* on_bb  = (const float*)d_in[16];
    const float* on_m   = (const float*)d_in[17];
    const float* on_v   = (const float*)d_in[18];
    const float* ff_w   = (const float*)d_in[19];
    const float* ff_b   = (const float*)d_in[20];
    const float* ff_g   = (const float*)d_in[21];
    const float* ff_bb  = (const float*)d_in[22];
    const float* ff_m   = (const float*)d_in[23];
    const float* ff_v   = (const float*)d_in[24];
    float* out = (float*)d_out;

    float* g_ws    = (float*)d_ws;                         // 26,738,688 f
    float* qk_ws   = g_ws   + (size_t)N_ * CTV_;           // 40,108,032 f
    float* part_ws = qk_ws  + (size_t)N_ * 96 * TV_;       //  3,145,728 f
    float* att_ws  = part_ws + (size_t)8 * NH_ * 4096;     //    393,216 f
    __bf16* P_bf   = (__bf16*)qk_ws;                       // alias (qk dead after k3a)
    __bf16* Apad   = (__bf16*)part_ws;                     // alias (dead before k3a writes)
    __bf16* Wbf    = Apad + (size_t)UP_ * KP_;             // alias (dead before k3a writes)
    __bf16* Wg     = Wbf + (size_t)96 * C_;                // alias (dead before k3a writes)
    __bf16* att_bt = (__bf16*)att_ws;                      // 786 KB (bf16 transposed att)
    __bf16* onw_bf = (__bf16*)att_ws + (size_t)NH_ * 4096; // +24 KB, survives k3
    __bf16* Wf     = onw_bf + (size_t)192 * C_;            // +8 KB, survives to k5

    k0_all<<<dim3(286), 256, 0, stream>>>(A, qkv_w, on_w, gcn_w, ff_w,
                                          Apad, Wbf, onw_bf, Wg, Wf);
    k1_fused<<<dim3(T_, N_), 256, 0, stream>>>(x, Wg, gcn_b, Apad,
                                               gcn_g, gcn_bb, gcn_m, gcn_v, g_ws);
    k2_mfma<<<dim3(6528), 256, 0, stream>>>(g_ws, pe, Wbf, qkv_b, qk_ws);
    k3_att_part<<<dim3(8, N_, 12), 64, 0, stream>>>(qk_ws, part_ws);
    k3_att_fin<<<dim3((NH_ * 4096) / 256), 256, 0, stream>>>(part_ws, alphas, att1s, att_bt);

    for (int chunk = 0; chunk < 2; ++chunk) {
        const int nb = chunk * 16;
        k4a_mfma<<<dim3(204, 16), 256, 0, stream>>>(
            g_ws + (size_t)nb * CTV_, onw_bf, P_bf);
        k4b_mfma<<<dim3(64, 16), 256, 0, stream>>>(
            P_bf, att_bt + (size_t)nb * 64 * 192, g_ws + (size_t)nb * CTV_,
            on_b, on_g, on_bb, on_m, on_v, out + (size_t)nb * CTV_);
    }
    k5_mfma<<<dim3(6528), 256, 0, stream>>>(g_ws, Wf, ff_b,
                                            ff_g, ff_bb, ff_m, ff_v, out);
}